// Round 6
// baseline (1648.494 us; speedup 1.0000x reference)
//
#include <hip/hip_runtime.h>

// B=64, S=512, I=256, O=256 fp32 LSTM.
// out = [h_seq (64*512*256)] [hT (64*256)] [cT (64*256)]
//
// Phase A: xg = x @ Wx^T + bx + bh  (fp32 LDS-tiled GEMM, known-good)
// Phase B (MFMA scan, spill-free budget): 64 blocks x 1 batch, 256 threads
//   = 4 waves = 1 wave/SIMD -> 512 unified regs/wave. Wave w owns 64 p-rows
//   per gate (16 16-row tiles). k<192 as A-frags in regs: 16x6 v8h = 384
//   regs. k in [192,256): fp16 in LDS (128 KB = the LDS cap for 64 k-cols).
//   Two j-passes reuse D[8] (32 regs) -> total ~480 < 512, no spill.
//   Per step: Bf = h(t-1) fp16 broadcast from LDS; 128 MFMA/wave; masked
//   scatter of y to ylds; barrier; dense gate phase (1 c-update/thread);
//   h -> double-buffered hbuf; barrier. Deferred h_seq store + xg loads
//   issued at step top so the barrier's implicit vmcnt(0) drain is hidden
//   under the ~2700-cyc MFMA/LDS phase.

#define SS 512

typedef _Float16 v8h __attribute__((ext_vector_type(8)));
typedef float vf4 __attribute__((ext_vector_type(4)));

__device__ __forceinline__ float sigm(float x) { return 1.f / (1.f + __expf(-x)); }
__device__ __forceinline__ float tanh_f(float x) {
  float e = __expf(-2.f * fabsf(x));
  float r = (1.f - e) / (1.f + e);
  return copysignf(r, x);
}

// ---------------------------------------------------------------- Phase A
__global__ __launch_bounds__(256) void xg_gemm(
    const float* __restrict__ X, const float* __restrict__ W,
    const float* __restrict__ bx, const float* __restrict__ bh,
    float* __restrict__ out)
{
  __shared__ float As[64][68];
  __shared__ float Bs[64][68];
  const int bm = blockIdx.x >> 4;
  const int bn = blockIdx.x & 15;
  const int tid = threadIdx.x;
  const int tn = tid & 15, tm = tid >> 4;
  const int row0 = bm * 64, col0 = bn * 64;
  float acc[4][4] = {};

  for (int k0 = 0; k0 < 256; k0 += 64) {
#pragma unroll
    for (int i = 0; i < 4; i++) {
      const int m = (tid >> 4) + i * 16;
      const int k = (tid & 15) * 4;
      float4 av = *(const float4*)&X[(size_t)(row0 + m) * 256 + k0 + k];
      *(float4*)&As[m][k] = av;
      float4 wv = *(const float4*)&W[(size_t)(col0 + m) * 256 + k0 + k];
      Bs[k + 0][m] = wv.x; Bs[k + 1][m] = wv.y;
      Bs[k + 2][m] = wv.z; Bs[k + 3][m] = wv.w;
    }
    __syncthreads();
#pragma unroll 8
    for (int kk = 0; kk < 64; kk++) {
      const float a0 = As[tm * 4 + 0][kk];
      const float a1 = As[tm * 4 + 1][kk];
      const float a2 = As[tm * 4 + 2][kk];
      const float a3 = As[tm * 4 + 3][kk];
      const float4 bv = *(const float4*)&Bs[kk][tn * 4];
      acc[0][0] = fmaf(a0, bv.x, acc[0][0]); acc[0][1] = fmaf(a0, bv.y, acc[0][1]);
      acc[0][2] = fmaf(a0, bv.z, acc[0][2]); acc[0][3] = fmaf(a0, bv.w, acc[0][3]);
      acc[1][0] = fmaf(a1, bv.x, acc[1][0]); acc[1][1] = fmaf(a1, bv.y, acc[1][1]);
      acc[1][2] = fmaf(a1, bv.z, acc[1][2]); acc[1][3] = fmaf(a1, bv.w, acc[1][3]);
      acc[2][0] = fmaf(a2, bv.x, acc[2][0]); acc[2][1] = fmaf(a2, bv.y, acc[2][1]);
      acc[2][2] = fmaf(a2, bv.z, acc[2][2]); acc[2][3] = fmaf(a2, bv.w, acc[2][3]);
      acc[3][0] = fmaf(a3, bv.x, acc[3][0]); acc[3][1] = fmaf(a3, bv.y, acc[3][1]);
      acc[3][2] = fmaf(a3, bv.z, acc[3][2]); acc[3][3] = fmaf(a3, bv.w, acc[3][3]);
    }
    __syncthreads();
  }

  float bias[4];
#pragma unroll
  for (int j = 0; j < 4; j++) {
    const int col = col0 + tn * 4 + j;
    bias[j] = bx[col] + bh[col];
  }
#pragma unroll
  for (int i = 0; i < 4; i++) {
    float4 o4;
    o4.x = acc[i][0] + bias[0]; o4.y = acc[i][1] + bias[1];
    o4.z = acc[i][2] + bias[2]; o4.w = acc[i][3] + bias[3];
    *(float4*)&out[(size_t)(row0 + tm * 4 + i) * 1024 + col0 + tn * 4] = o4;
  }
}

// ---------------------------------------------------------------- Phase B
__global__ __launch_bounds__(256, 1) void lstm_scan6(
    const float* __restrict__ xg,   // [64][512][1024]
    const float* __restrict__ Wh,   // [1024][256]  row = g*256+p, col = k
    const float* __restrict__ h0,   // [64][256]
    const float* __restrict__ c0,   // [64][256]
    float* __restrict__ out)
{
  __shared__ __align__(16) _Float16 wtail[4][16][2][64][8];  // 128 KB
  __shared__ __align__(16) _Float16 hbuf[2][256];            // 1 KB
  __shared__ __align__(16) float ylds[4][256];               // 4 KB

  const int tid  = threadIdx.x;
  const int b    = blockIdx.x;
  const int w    = tid >> 6;
  const int lane = tid & 63;
  const int q    = lane >> 4;
  const int l15  = lane & 15;

  // ---- A-frags k<192 (384 regs); tail k in [192,256) -> LDS (self-swizzled)
  v8h A[16][6];
#pragma unroll
  for (int j = 0; j < 16; ++j) {
    const int g = j >> 2, i = j & 3;
    const float* rp = Wh + (size_t)(g * 256 + w * 64 + i * 16 + l15) * 256 + q * 8;
#pragma unroll
    for (int kf = 0; kf < 6; ++kf) {
      float4 lo = *(const float4*)(rp + kf * 32);
      float4 hi = *(const float4*)(rp + kf * 32 + 4);
      v8h a;
      a[0] = (_Float16)lo.x; a[1] = (_Float16)lo.y;
      a[2] = (_Float16)lo.z; a[3] = (_Float16)lo.w;
      a[4] = (_Float16)hi.x; a[5] = (_Float16)hi.y;
      a[6] = (_Float16)hi.z; a[7] = (_Float16)hi.w;
      A[j][kf] = a;
    }
#pragma unroll
    for (int kfi = 0; kfi < 2; ++kfi) {
      float4 lo = *(const float4*)(rp + 192 + kfi * 32);
      float4 hi = *(const float4*)(rp + 192 + kfi * 32 + 4);
      _Float16* dst = &wtail[w][j][kfi][lane][0];
      dst[0] = (_Float16)lo.x; dst[1] = (_Float16)lo.y;
      dst[2] = (_Float16)lo.z; dst[3] = (_Float16)lo.w;
      dst[4] = (_Float16)hi.x; dst[5] = (_Float16)hi.y;
      dst[6] = (_Float16)hi.z; dst[7] = (_Float16)hi.w;
    }
  }

  hbuf[0][tid] = (_Float16)h0[(size_t)b * 256 + tid];
  float c = c0[(size_t)b * 256 + tid];
  __syncthreads();

  const float* xb = xg + (size_t)b * SS * 1024;
  float* hs = out + (size_t)b * SS * 256;
  float hprev = 0.f;

  for (int t = 0; t < SS; ++t) {
    const int par = t & 1;

    // issue global traffic first: deferred h_seq store + this step's xg loads
    if (t > 0) hs[(size_t)(t - 1) * 256 + tid] = hprev;
    const float* xp = xb + (size_t)t * 1024 + tid;
    const float xc0 = xp[0], xc1 = xp[256], xc2 = xp[512], xc3 = xp[768];

    // ---- MFMA phase: two passes of 8 j-tiles, D[8] reused
#pragma unroll
    for (int pass = 0; pass < 2; ++pass) {
      vf4 D[8];
#pragma unroll
      for (int jj = 0; jj < 8; ++jj) { vf4 z = {0.f, 0.f, 0.f, 0.f}; D[jj] = z; }
      // k < 192: A in regs
#pragma unroll
      for (int kf = 0; kf < 6; ++kf) {
        v8h Bf = *(const v8h*)&hbuf[par][kf * 32 + q * 8];
#pragma unroll
        for (int jj = 0; jj < 8; ++jj)
          D[jj] = __builtin_amdgcn_mfma_f32_16x16x32_f16(
              A[pass * 8 + jj][kf], Bf, D[jj], 0, 0, 0);
      }
      // k in [192,256): A streamed from LDS
#pragma unroll
      for (int kfi = 0; kfi < 2; ++kfi) {
        v8h Bf = *(const v8h*)&hbuf[par][(6 + kfi) * 32 + q * 8];
#pragma unroll
        for (int jj = 0; jj < 8; ++jj) {
          v8h wt = *(const v8h*)&wtail[w][pass * 8 + jj][kfi][lane][0];
          D[jj] = __builtin_amdgcn_mfma_f32_16x16x32_f16(wt, Bf, D[jj], 0, 0, 0);
        }
      }
      // scatter y rows (col 0 lanes)
      if (l15 == 0) {
#pragma unroll
        for (int jj = 0; jj < 8; ++jj) {
          const int j = pass * 8 + jj, g = j >> 2, i = j & 3;
          *(vf4*)&ylds[g][w * 64 + i * 16 + q * 4] = D[jj];
        }
      }
    }
    __syncthreads();

    // ---- dense gate phase: every thread one c-update (p = tid)
    const float y0 = ylds[0][tid] + xc0;   // f
    const float y1 = ylds[1][tid] + xc1;   // i
    const float y2 = ylds[2][tid] + xc2;   // g
    const float y3 = ylds[3][tid] + xc3;   // o
    const float fg = sigm(y0);
    const float ig = sigm(y1);
    const float gt = tanh_f(y2);
    const float og = sigm(y3);
    c = c * fg + ig * gt;
    const float h = og * tanh_f(c);
    hprev = h;
    hbuf[par ^ 1][tid] = (_Float16)h;
    __syncthreads();
  }

  hs[(size_t)(SS - 1) * 256 + tid] = hprev;
  out[8388608 + (size_t)b * 256 + tid] = hprev;   // hT
  out[8404992 + (size_t)b * 256 + tid] = c;       // cT
}

// ---------------------------------------------------------------- launch
extern "C" void kernel_launch(void* const* d_in, const int* in_sizes, int n_in,
                              void* d_out, int out_size, void* d_ws, size_t ws_size,
                              hipStream_t stream) {
  const float* x  = (const float*)d_in[0];
  const float* h0 = (const float*)d_in[1];
  const float* c0 = (const float*)d_in[2];
  const float* Wh = (const float*)d_in[3];
  const float* bh = (const float*)d_in[4];
  const float* Wx = (const float*)d_in[5];
  const float* bx = (const float*)d_in[6];
  float* out = (float*)d_out;

  float* xg = (float*)d_ws;   // 32768*1024 floats = 128 MB

  xg_gemm<<<dim3(8192), dim3(256), 0, stream>>>(x, Wx, bx, bh, xg);
  lstm_scan6<<<dim3(64), dim3(256), 0, stream>>>(xg, Wh, h0, c0, out);
}